// Round 9
// baseline (121.389 us; speedup 1.0000x reference)
//
#include <hip/hip_runtime.h>
#include <hip/hip_bf16.h>

// 3D shifted-window attention (Swin), D=H=W=32, WS=8, SS=4, NH=12, HD=32, N=512.
// Pass 1 (prep): [blocks 0..4095] repack qkv fp32 -> bf16:
//                  Q: g_pack[0][nh][w][m][hd]          (pre-scaled scale*log2e)
//                  K: g_pack[1][nh][w][m][hd^swz]      (XOR-swizzle pre-baked)
//                  V: g_pack[2][nh][w][mb8][hd][8]     (8-token tiles, attn-ready)
//                Load phase register-staged (float4 buf[9] -> 9 outstanding loads;
//                round-8's 24-VGPR version serialized them = 1.9 TB/s).
//                [blocks 4096..5631] bias -> fp32 g_biasC (bias*log2e) in exact
//                S^T D-fragment order, fed to the QK MFMA as the C operand.
// Pass 2 (attn): one block per (window,head), 512 thr, 8 waves x 4 q-tiles.
//         K + V^T staged to LDS by pure linear copies (transposes pre-baked).
//         Per c: load K/V frags once, feed 4 q-tiles. acc = mfma(K,Q,biasC);
//         p = v_exp_f32(acc); pack (cvt_pk); row-sum via ones-MFMA; mask via
//         cndmask on packed words; o += mfma(Vt, pf). setprio(1) around core.
//         Output -> g_opack (bf16) [nh][w][qt][hd][tk16].
// Pass 3: unpack g_opack (bf16) -> out[vox][hd*12+nh] fp32 via LDS transpose.

typedef __attribute__((ext_vector_type(8))) short short8_t;   // 8 x bf16
typedef __attribute__((ext_vector_type(4))) float f32x4;

__device__ float g_biasC[12 * 32 * 16 * 64 * 8];              // 12.6 MB fp32
__device__ uint4 g_pack4[3ULL * 12 * 64 * 512 * 32 / 8];      // 75.5 MB bf16
__device__ unsigned short g_opack[12ULL * 64 * 32 * 512];     // 25.2 MB bf16

constexpr float SCL2E = 0.17677669529663687f * 1.4426950408889634f; // scale*log2e
constexpr float LOG2E = 1.4426950408889634f;

__device__ __forceinline__ unsigned short f2bf(float f) {
  __hip_bfloat16 h = __float2bfloat16(f);   // RNE
  return *reinterpret_cast<unsigned short*>(&h);
}
__device__ __forceinline__ unsigned pkbf2(float lo, float hi) {
  __hip_bfloat162 h2 = __float22bfloat162_rn(make_float2(lo, hi)); // v_cvt_pk_bf16_f32
  return *reinterpret_cast<unsigned*>(&h2);
}

// ---------------- pass 1: repack + bias prep (merged grid) ----------------
__global__ __launch_bounds__(256, 4) void prep_kernel(
    const float* __restrict__ qkv, const float* __restrict__ table) {
  __shared__ unsigned short S[8 * 1154];
  const int bid = blockIdx.x;
  const int tid = threadIdx.x;

  if (bid >= 4096) {
    // ---- bias part: g_biasC[flat*8 + e] = bias(n, m(e)) * log2e, fp32 ----
    int flat = (bid - 4096) * 256 + tid;    // 0..393215 = (nh, qt, c, lane)
    int l  = flat & 63;
    int c  = (flat >> 6) & 15;
    int qt = (flat >> 10) & 31;
    int nh = flat >> 15;
    int ln = l & 15, g = l >> 4;
    int n = qt * 16 + ln;
    int dn = n >> 6, hn = (n >> 3) & 7, wn = n & 7;
    float e[8];
#pragma unroll
    for (int r = 0; r < 8; ++r) {
      int m = 32 * c + (r >> 2) * 16 + g * 4 + (r & 3);
      int dm = m >> 6, hm = (m >> 3) & 7, wm = m & 7;
      int idx = (dn - dm + 7) * 225 + (hn - hm + 7) * 15 + (wn - wm + 7);
      e[r] = table[idx * 12 + nh] * LOG2E;
    }
    *(float4*)&g_biasC[flat * 8]     = make_float4(e[0], e[1], e[2], e[3]);
    *(float4*)&g_biasC[flat * 8 + 4] = make_float4(e[4], e[5], e[6], e[7]);
    return;
  }

  // ---- repack part ----
  const int mh = bid & 7;
  const int md = (bid >> 3) & 7;
  const int w = bid >> 6;
  const int dblk = w >> 4, hblk = (w >> 2) & 3, wblk = w & 3;
  const int dd = (dblk * 8 + 4 + md) & 31;
  const int hh = (hblk * 8 + 4 + mh) & 31;
  const int w0 = wblk * 8 + 4;

  // load phase: all 9 loads issued before any use (9 outstanding -> latency
  // amortized; round-8's fused loop had 1 outstanding at VGPR=24)
  float4 buf[9];
#pragma unroll
  for (int rep = 0; rep < 9; ++rep) {
    int t = rep * 256 + tid;
    unsigned v = (unsigned)t / 288u;
    int c4 = t - (int)v * 288;
    int ww = (w0 + (int)v) & 31;
    buf[rep] = *(const float4*)(qkv + (((dd * 32 + hh) * 32 + ww) * 1152) + c4 * 4);
  }
#pragma unroll
  for (int rep = 0; rep < 9; ++rep) {
    int t = rep * 256 + tid;
    unsigned v = (unsigned)t / 288u;
    int c4 = t - (int)v * 288;
    float4 f = buf[rep];
    const float sc = (c4 < 96) ? SCL2E : 1.0f;   // Q channels pre-scaled
    f.x *= sc; f.y *= sc; f.z *= sc; f.w *= sc;
    *(uint2*)&S[v * 1154 + c4 * 4] = make_uint2(pkbf2(f.x, f.y), pkbf2(f.z, f.w));
  }
  __syncthreads();

  const int mbase = md * 64 + mh * 8;
  unsigned short* gp = (unsigned short*)g_pack4;
#pragma unroll
  for (int rep = 0; rep < 5; ++rep) {
    int t = rep * 256 + tid;                 // 1152 tasks
    if (t < 1152) {
      int r = t >> 5;                        // 0..35
      int nh = r % 12;
      int part = r / 12;
      unsigned pk[4];
      size_t dst;
      if (part < 2) {
        // Q/K: pack 8 consecutive hd of one token
        int chunk = t & 3;
        int mw = (t >> 2) & 7;
        int ebase = mw * 1154 + part * 384 + chunk * 96 + nh;
#pragma unroll
        for (int jj = 0; jj < 4; ++jj) {
          unsigned lo = S[ebase + (2 * jj) * 12];
          unsigned hi = S[ebase + (2 * jj + 1) * 12];
          pk[jj] = lo | (hi << 16);
        }
        int m = mbase + mw;
        int off = (part == 0) ? (m * 32 + chunk * 8)
                              : (m * 32 + ((chunk * 8) ^ ((mw & 3) << 3))); // K swz
        dst = ((size_t)(part * 12 + nh) * 64 + w) * 16384 + off;
      } else {
        // V: pack 8 consecutive tokens of one hd -> [mb8][hd][8] tile
        int hd = t & 31;
        int ebase = 768 + hd * 12 + nh;
#pragma unroll
        for (int jj = 0; jj < 4; ++jj) {
          unsigned lo = S[(2 * jj) * 1154 + ebase];
          unsigned hi = S[(2 * jj + 1) * 1154 + ebase];
          pk[jj] = lo | (hi << 16);
        }
        dst = ((size_t)(24 + nh) * 64 + w) * 16384 + (md * 8 + mh) * 256 + hd * 8;
      }
      *(uint4*)&gp[dst] = make_uint4(pk[0], pk[1], pk[2], pk[3]);
    }
  }
}

// -------- pass 2: attention (512 threads, 8 waves x 4 q-tiles, fused) --------
__global__ __launch_bounds__(512, 4) void swin_attn_kernel() {
  __shared__ __align__(16) unsigned short Klds[512 * 32];   // 32 KB, XOR-swz
  __shared__ __align__(16) unsigned short Vt[32 * 516];     // 33 KB

  const int bid = blockIdx.x;
  // Head-clustered XCD map: XCD x owns head x (64 windows) + half of head 8+x/2
  const int xcd = bid & 7;
  const int jb = bid >> 3;                   // 0..95
  int nh, w;
  if (jb < 64) { nh = xcd; w = jb; }
  else         { nh = 8 + (xcd >> 1); w = (xcd & 1) * 32 + (jb - 64); }
  const int dblk = w >> 4, hblk = (w >> 2) & 3, wblk = w & 3;
  const int bm = ((dblk == 3) ? 256 : 0) | ((hblk == 3) ? 32 : 0) |
                 ((wblk == 3) ? 4 : 0);

  const int tid = threadIdx.x;

  const unsigned short* gp = (const unsigned short*)g_pack4;
  const size_t base = ((size_t)nh * 64 + w) * (512 * 32);
  const unsigned short* Qg = gp + base;                           // part 0
  const unsigned short* Kg = gp + (size_t)1 * 12 * 64 * 512 * 32 + base;
  const unsigned short* Vg = gp + (size_t)2 * 12 * 64 * 512 * 32 + base;

  // ---- stage K + V: 8 outstanding linear uint4 loads, then LDS writes ----
  uint4 kb[4], vb[4];
#pragma unroll
  for (int itr = 0; itr < 4; ++itr) kb[itr] = *(const uint4*)(Kg + (itr * 512 + tid) * 8);
#pragma unroll
  for (int itr = 0; itr < 4; ++itr) vb[itr] = *(const uint4*)(Vg + (itr * 512 + tid) * 8);
#pragma unroll
  for (int itr = 0; itr < 4; ++itr)
    *(uint4*)((char*)Klds + (itr * 512 + tid) * 16) = kb[itr];   // swz pre-baked
#pragma unroll
  for (int itr = 0; itr < 4; ++itr) {
    int flat = itr * 512 + tid;
    int hd = flat & 31, mb8 = flat >> 5;
    *(uint2*)&Vt[hd * 516 + mb8 * 8]     = make_uint2(vb[itr].x, vb[itr].y);
    *(uint2*)&Vt[hd * 516 + mb8 * 8 + 4] = make_uint2(vb[itr].z, vb[itr].w);
  }
  __syncthreads();

  const int l = tid & 63;
  const int wv = tid >> 6;                   // 0..7, owns q-tiles wv*4..wv*4+3
  const int ln = l & 15;
  const int g = l >> 4;

  union frag { unsigned u[4]; short8_t v; };

  // Q fragments for the wave's 4 q-tiles (Q already pre-scaled)
  frag qf[4];
#pragma unroll
  for (int it = 0; it < 4; ++it) {
    const int n = (wv * 4 + it) * 16 + ln;
    const uint4 qd = *(const uint4*)(Qg + n * 32 + g * 8);
    qf[it].u[0] = qd.x; qf[it].u[1] = qd.y; qf[it].u[2] = qd.z; qf[it].u[3] = qd.w;
  }
  f32x4 o0[4], o1[4], sumac[4];
#pragma unroll
  for (int it = 0; it < 4; ++it) {
    o0[it] = (f32x4)(0.0f); o1[it] = (f32x4)(0.0f); sumac[it] = (f32x4)(0.0f);
  }
  frag ones;
  ones.u[0] = 0x3F803F80u; ones.u[1] = 0x3F803F80u;
  ones.u[2] = 0x3F803F80u; ones.u[3] = 0x3F803F80u;

  // bias fragment stream (fp32, D-fragment order)
  const f32x4* bp = (const f32x4*)g_biasC +
      ((size_t)(nh * 32 + wv * 4) * 16) * 128 + l * 2;

  int nA[4];
#pragma unroll
  for (int it = 0; it < 4; ++it) nA[it] = ((wv * 4 + it) * 16 + ln) & bm;

#define CLOOP(MASKED)                                                          \
  _Pragma("unroll 1")                                                          \
  for (int c = 0; c < 16; ++c) {                                               \
    frag k0, k1, a0, a1;                                                       \
    k0.v = *(const short8_t*)((const char*)Klds +                              \
        (((2 * c) * 16 + ln) * 64 + ((g * 16) ^ ((ln & 3) << 4))));            \
    k1.v = *(const short8_t*)((const char*)Klds +                              \
        (((2 * c + 1) * 16 + ln) * 64 + ((g * 16) ^ ((ln & 3) << 4))));        \
    {                                                                          \
      const int col = c * 32 + g * 4;                                          \
      const unsigned* v00 = (const unsigned*)&Vt[ln * 516 + col];              \
      const unsigned* v01 = (const unsigned*)&Vt[ln * 516 + col + 16];         \
      a0.u[0] = v00[0]; a0.u[1] = v00[1]; a0.u[2] = v01[0]; a0.u[3] = v01[1];  \
      const unsigned* v10 = (const unsigned*)&Vt[(16 + ln) * 516 + col];       \
      const unsigned* v11 = (const unsigned*)&Vt[(16 + ln) * 516 + col + 16];  \
      a1.u[0] = v10[0]; a1.u[1] = v10[1]; a1.u[2] = v11[0]; a1.u[3] = v11[1];  \
    }                                                                          \
    const int mAnd = ((c << 5) | ((g & 1) << 2)) & bm;                         \
    __builtin_amdgcn_s_setprio(1);                                             \
    _Pragma("unroll")                                                          \
    for (int it = 0; it < 4; ++it) {                                           \
      const f32x4 bc0 = bp[(it * 16 + c) * 128];                               \
      const f32x4 bc1 = bp[(it * 16 + c) * 128 + 1];                           \
      f32x4 acc0 = __builtin_amdgcn_mfma_f32_16x16x32_bf16(                    \
          k0.v, qf[it].v, bc0, 0, 0, 0);                                       \
      f32x4 acc1 = __builtin_amdgcn_mfma_f32_16x16x32_bf16(                    \
          k1.v, qf[it].v, bc1, 0, 0, 0);                                       \
      float p0 = __builtin_amdgcn_exp2f(acc0[0]);                              \
      float p1 = __builtin_amdgcn_exp2f(acc0[1]);                              \
      float p2 = __builtin_amdgcn_exp2f(acc0[2]);                              \
      float p3 = __builtin_amdgcn_exp2f(acc0[3]);                              \
      float p4 = __builtin_amdgcn_exp2f(acc1[0]);                              \
      float p5 = __builtin_amdgcn_exp2f(acc1[1]);                              \
      float p6 = __builtin_amdgcn_exp2f(acc1[2]);                              \
      float p7 = __builtin_amdgcn_exp2f(acc1[3]);                              \
      frag pf;                                                                 \
      pf.u[0] = pkbf2(p0, p1);  pf.u[1] = pkbf2(p2, p3);                       \
      pf.u[2] = pkbf2(p4, p5);  pf.u[3] = pkbf2(p6, p7);                       \
      if (MASKED) {                                                            \
        const bool keep = (nA[it] == mAnd);                                    \
        pf.u[0] = keep ? pf.u[0] : 0u;                                         \
        pf.u[1] = keep ? pf.u[1] : 0u;                                         \
        pf.u[2] = keep ? pf.u[2] : 0u;                                         \
        pf.u[3] = keep ? pf.u[3] : 0u;                                         \
      }                                                                        \
      sumac[it] = __builtin_amdgcn_mfma_f32_16x16x32_bf16(                     \
          ones.v, pf.v, sumac[it], 0, 0, 0);                                   \
      o0[it] = __builtin_amdgcn_mfma_f32_16x16x32_bf16(a0.v, pf.v, o0[it], 0, 0, 0); \
      o1[it] = __builtin_amdgcn_mfma_f32_16x16x32_bf16(a1.v, pf.v, o1[it], 0, 0, 0); \
    }                                                                          \
    __builtin_amdgcn_s_setprio(0);                                             \
  }

  if (bm == 0) { CLOOP(false) } else { CLOOP(true) }
#undef CLOOP

  // ---- epilogue: every lane's sumac[it][0] is its own full row-sum ----
#pragma unroll
  for (int it = 0; it < 4; ++it) {
    const float rinv = 1.0f / sumac[it][0];
    const int qt = wv * 4 + it;
    unsigned short* gop = g_opack + ((size_t)nh * 64 + w) * 16384 + qt * 512 + ln;
#pragma unroll
    for (int r = 0; r < 4; ++r) {
      gop[(g * 4 + r) * 16] = f2bf(o0[it][r] * rinv);
      gop[(g * 4 + r + 16) * 16] = f2bf(o1[it][r] * rinv);
    }
  }
}

// ---------------- pass 3: unpack g_opack (bf16) -> out (fp32) ----------------
__global__ __launch_bounds__(256) void unpack_kernel(float* __restrict__ out) {
  __shared__ float S[32 * 388];             // 48.5 KB
  const int bid = blockIdx.x;               // 64*16 = 1024
  const int mc = bid & 15;
  const int w = bid >> 4;
  const int dblk = w >> 4, hblk = (w >> 2) & 3, wblk = w & 3;
  const int d0 = dblk * 8 + 4, h0 = hblk * 8 + 4, w0 = wblk * 8 + 4;
  const int tid = threadIdx.x;

  // load: gop[nh][w][qt][hd][tk16] (bf16) -> S[ml][hd*12+nh] (f32)
#pragma unroll
  for (int rep = 0; rep < 6; ++rep) {
    int task = rep * 256 + tid;             // 0..1535
    int tk8 = task & 1;
    int q2 = (task >> 1) & 1;
    int hd = (task >> 2) & 31;
    int nh = task >> 7;                     // 0..11
    const uint4 d = *(const uint4*)(g_opack +
        ((size_t)nh * 64 + w) * 16384 + (size_t)(mc * 2 + q2) * 512 + hd * 16 + tk8 * 8);
    const unsigned u[4] = {d.x, d.y, d.z, d.w};
#pragma unroll
    for (int jj = 0; jj < 8; ++jj) {
      unsigned bits = (u[jj >> 1] << (16 * (1 - (jj & 1)))) & 0xffff0000u;
      S[(q2 * 16 + tk8 * 8 + jj) * 388 + hd * 12 + nh] = __uint_as_float(bits);
    }
  }
  __syncthreads();

  // store: token-major, fully coalesced full-line writes
#pragma unroll
  for (int rep = 0; rep < 12; ++rep) {
    int task = rep * 256 + tid;             // 0..3071
    unsigned c4 = (unsigned)task % 96u;
    int ml = (int)((unsigned)task / 96u);
    int n = mc * 32 + ml;
    int dd = (d0 + (n >> 6)) & 31;
    int hh = (h0 + ((n >> 3) & 7)) & 31;
    int ww = (w0 + (n & 7)) & 31;
    const float4* src = (const float4*)&S[ml * 388 + c4 * 4];
    *(float4*)(out + ((size_t)((dd * 32 + hh) * 32 + ww)) * 384 + c4 * 4) = *src;
  }
}

extern "C" void kernel_launch(void* const* d_in, const int* in_sizes, int n_in,
                              void* d_out, int out_size, void* d_ws, size_t ws_size,
                              hipStream_t stream) {
  (void)in_sizes; (void)n_in; (void)out_size; (void)d_ws; (void)ws_size;
  const float* qkv = (const float*)d_in[0];          // [1,32,32,32,1152] fp32
  const float* bias_table = (const float*)d_in[1];   // [3375,12] fp32
  float* out = (float*)d_out;                        // [1,32,32,32,384] fp32

  prep_kernel<<<5632, 256, 0, stream>>>(qkv, bias_table);
  swin_attn_kernel<<<768, 512, 0, stream>>>();
  unpack_kernel<<<1024, 256, 0, stream>>>(out);
}

// Round 10
// 121.207 us; speedup vs baseline: 1.0015x; 1.0015x over previous
//
#include <hip/hip_runtime.h>
#include <hip/hip_bf16.h>

// 3D shifted-window attention (Swin), D=H=W=32, WS=8, SS=4, NH=12, HD=32, N=512.
// Pass 1 (prep): [blocks 0..4095] repack qkv fp32 -> bf16:
//                  Q: g_pack[0][nh][w][m][hd]          (pre-scaled scale*log2e)
//                  K: g_pack[1][nh][w][m][hd^swz]      (XOR-swizzle pre-baked)
//                  V: g_pack[2][nh][w][mb8][hd][8]     (8-token tiles, attn-ready)
//                Load phase register-staged with asm register-pin + sched_barrier
//                (round-9's plain buf[9] was re-fused by the scheduler: VGPR=28,
//                1 outstanding load, 2 TB/s. The asm pin forces all 9 in flight.)
//                [blocks 4096..5631] bias -> fp32 g_biasC (bias*log2e) in exact
//                S^T D-fragment order, fed to the QK MFMA as the C operand.
// Pass 2 (attn): one block per (window,head), 512 thr, 8 waves x 4 q-tiles.
//         K + V^T staged to LDS by pure linear copies (transposes pre-baked).
//         Per c: load K/V frags once, feed 4 q-tiles. acc = mfma(K,Q,biasC);
//         p = v_exp_f32(acc); pack (cvt_pk); row-sum via ones-MFMA; mask via
//         cndmask on packed words; o += mfma(Vt, pf). setprio(1) around core.
//         Output -> g_opack (bf16) [nh][w][qt][hd][tk16].
// Pass 3: unpack g_opack (bf16) -> out[vox][hd*12+nh] fp32 via LDS transpose.

typedef __attribute__((ext_vector_type(8))) short short8_t;   // 8 x bf16
typedef __attribute__((ext_vector_type(4))) float f32x4;

__device__ float g_biasC[12 * 32 * 16 * 64 * 8];              // 12.6 MB fp32
__device__ uint4 g_pack4[3ULL * 12 * 64 * 512 * 32 / 8];      // 75.5 MB bf16
__device__ unsigned short g_opack[12ULL * 64 * 32 * 512];     // 25.2 MB bf16

constexpr float SCL2E = 0.17677669529663687f * 1.4426950408889634f; // scale*log2e
constexpr float LOG2E = 1.4426950408889634f;

__device__ __forceinline__ unsigned short f2bf(float f) {
  __hip_bfloat16 h = __float2bfloat16(f);   // RNE
  return *reinterpret_cast<unsigned short*>(&h);
}
__device__ __forceinline__ unsigned pkbf2(float lo, float hi) {
  __hip_bfloat162 h2 = __float22bfloat162_rn(make_float2(lo, hi)); // v_cvt_pk_bf16_f32
  return *reinterpret_cast<unsigned*>(&h2);
}
__device__ __forceinline__ void pin4(float4& f) {
  asm volatile("" : "+v"(f.x), "+v"(f.y), "+v"(f.z), "+v"(f.w));
}
__device__ __forceinline__ void pinu4(uint4& u) {
  asm volatile("" : "+v"(u.x), "+v"(u.y), "+v"(u.z), "+v"(u.w));
}

// ---------------- pass 1: repack + bias prep (merged grid) ----------------
__global__ __launch_bounds__(256, 4) void prep_kernel(
    const float* __restrict__ qkv, const float* __restrict__ table) {
  __shared__ unsigned short S[8 * 1154];
  const int bid = blockIdx.x;
  const int tid = threadIdx.x;

  if (bid >= 4096) {
    // ---- bias part: g_biasC[flat*8 + e] = bias(n, m(e)) * log2e, fp32 ----
    int flat = (bid - 4096) * 256 + tid;    // 0..393215 = (nh, qt, c, lane)
    int l  = flat & 63;
    int c  = (flat >> 6) & 15;
    int qt = (flat >> 10) & 31;
    int nh = flat >> 15;
    int ln = l & 15, g = l >> 4;
    int n = qt * 16 + ln;
    int dn = n >> 6, hn = (n >> 3) & 7, wn = n & 7;
    float e[8];
#pragma unroll
    for (int r = 0; r < 8; ++r) {
      int m = 32 * c + (r >> 2) * 16 + g * 4 + (r & 3);
      int dm = m >> 6, hm = (m >> 3) & 7, wm = m & 7;
      int idx = (dn - dm + 7) * 225 + (hn - hm + 7) * 15 + (wn - wm + 7);
      e[r] = table[idx * 12 + nh];
    }
#pragma unroll
    for (int r = 0; r < 8; ++r) asm volatile("" : "+v"(e[r]));
    __builtin_amdgcn_sched_barrier(0);
#pragma unroll
    for (int r = 0; r < 8; ++r) e[r] *= LOG2E;
    *(float4*)&g_biasC[flat * 8]     = make_float4(e[0], e[1], e[2], e[3]);
    *(float4*)&g_biasC[flat * 8 + 4] = make_float4(e[4], e[5], e[6], e[7]);
    return;
  }

  // ---- repack part ----
  const int mh = bid & 7;
  const int md = (bid >> 3) & 7;
  const int w = bid >> 6;
  const int dblk = w >> 4, hblk = (w >> 2) & 3, wblk = w & 3;
  const int dd = (dblk * 8 + 4 + md) & 31;
  const int hh = (hblk * 8 + 4 + mh) & 31;
  const int w0 = wblk * 8 + 4;

  // load phase: all 9 loads issued and PINNED live before any use
  float4 buf[9];
#pragma unroll
  for (int rep = 0; rep < 9; ++rep) {
    int t = rep * 256 + tid;
    unsigned v = (unsigned)t / 288u;
    int c4 = t - (int)v * 288;
    int ww = (w0 + (int)v) & 31;
    buf[rep] = *(const float4*)(qkv + (((dd * 32 + hh) * 32 + ww) * 1152) + c4 * 4);
  }
#pragma unroll
  for (int rep = 0; rep < 9; ++rep) pin4(buf[rep]);
  __builtin_amdgcn_sched_barrier(0);
#pragma unroll
  for (int rep = 0; rep < 9; ++rep) {
    int t = rep * 256 + tid;
    unsigned v = (unsigned)t / 288u;
    int c4 = t - (int)v * 288;
    float4 f = buf[rep];
    const float sc = (c4 < 96) ? SCL2E : 1.0f;   // Q channels pre-scaled
    f.x *= sc; f.y *= sc; f.z *= sc; f.w *= sc;
    *(uint2*)&S[v * 1154 + c4 * 4] = make_uint2(pkbf2(f.x, f.y), pkbf2(f.z, f.w));
  }
  __syncthreads();

  const int mbase = md * 64 + mh * 8;
  unsigned short* gp = (unsigned short*)g_pack4;
#pragma unroll
  for (int rep = 0; rep < 5; ++rep) {
    int t = rep * 256 + tid;                 // 1152 tasks
    if (t < 1152) {
      int r = t >> 5;                        // 0..35
      int nh = r % 12;
      int part = r / 12;
      unsigned pk[4];
      size_t dst;
      if (part < 2) {
        // Q/K: pack 8 consecutive hd of one token
        int chunk = t & 3;
        int mw = (t >> 2) & 7;
        int ebase = mw * 1154 + part * 384 + chunk * 96 + nh;
#pragma unroll
        for (int jj = 0; jj < 4; ++jj) {
          unsigned lo = S[ebase + (2 * jj) * 12];
          unsigned hi = S[ebase + (2 * jj + 1) * 12];
          pk[jj] = lo | (hi << 16);
        }
        int m = mbase + mw;
        int off = (part == 0) ? (m * 32 + chunk * 8)
                              : (m * 32 + ((chunk * 8) ^ ((mw & 3) << 3))); // K swz
        dst = ((size_t)(part * 12 + nh) * 64 + w) * 16384 + off;
      } else {
        // V: pack 8 consecutive tokens of one hd -> [mb8][hd][8] tile
        int hd = t & 31;
        int ebase = 768 + hd * 12 + nh;
#pragma unroll
        for (int jj = 0; jj < 4; ++jj) {
          unsigned lo = S[(2 * jj) * 1154 + ebase];
          unsigned hi = S[(2 * jj + 1) * 1154 + ebase];
          pk[jj] = lo | (hi << 16);
        }
        dst = ((size_t)(24 + nh) * 64 + w) * 16384 + (md * 8 + mh) * 256 + hd * 8;
      }
      *(uint4*)&gp[dst] = make_uint4(pk[0], pk[1], pk[2], pk[3]);
    }
  }
}

// -------- pass 2: attention (512 threads, 8 waves x 4 q-tiles, fused) --------
__global__ __launch_bounds__(512, 4) void swin_attn_kernel() {
  __shared__ __align__(16) unsigned short Klds[512 * 32];   // 32 KB, XOR-swz
  __shared__ __align__(16) unsigned short Vt[32 * 516];     // 33 KB

  const int bid = blockIdx.x;
  // Head-clustered XCD map: XCD x owns head x (64 windows) + half of head 8+x/2
  const int xcd = bid & 7;
  const int jb = bid >> 3;                   // 0..95
  int nh, w;
  if (jb < 64) { nh = xcd; w = jb; }
  else         { nh = 8 + (xcd >> 1); w = (xcd & 1) * 32 + (jb - 64); }
  const int dblk = w >> 4, hblk = (w >> 2) & 3, wblk = w & 3;
  const int bm = ((dblk == 3) ? 256 : 0) | ((hblk == 3) ? 32 : 0) |
                 ((wblk == 3) ? 4 : 0);

  const int tid = threadIdx.x;

  const unsigned short* gp = (const unsigned short*)g_pack4;
  const size_t base = ((size_t)nh * 64 + w) * (512 * 32);
  const unsigned short* Qg = gp + base;                           // part 0
  const unsigned short* Kg = gp + (size_t)1 * 12 * 64 * 512 * 32 + base;
  const unsigned short* Vg = gp + (size_t)2 * 12 * 64 * 512 * 32 + base;

  // ---- stage K + V: 8 outstanding linear uint4 loads (pinned), LDS writes ----
  uint4 kb[4], vb[4];
#pragma unroll
  for (int itr = 0; itr < 4; ++itr) kb[itr] = *(const uint4*)(Kg + (itr * 512 + tid) * 8);
#pragma unroll
  for (int itr = 0; itr < 4; ++itr) vb[itr] = *(const uint4*)(Vg + (itr * 512 + tid) * 8);
#pragma unroll
  for (int itr = 0; itr < 4; ++itr) { pinu4(kb[itr]); pinu4(vb[itr]); }
  __builtin_amdgcn_sched_barrier(0);
#pragma unroll
  for (int itr = 0; itr < 4; ++itr)
    *(uint4*)((char*)Klds + (itr * 512 + tid) * 16) = kb[itr];   // swz pre-baked
#pragma unroll
  for (int itr = 0; itr < 4; ++itr) {
    int flat = itr * 512 + tid;
    int hd = flat & 31, mb8 = flat >> 5;
    *(uint2*)&Vt[hd * 516 + mb8 * 8]     = make_uint2(vb[itr].x, vb[itr].y);
    *(uint2*)&Vt[hd * 516 + mb8 * 8 + 4] = make_uint2(vb[itr].z, vb[itr].w);
  }
  __syncthreads();

  const int l = tid & 63;
  const int wv = tid >> 6;                   // 0..7, owns q-tiles wv*4..wv*4+3
  const int ln = l & 15;
  const int g = l >> 4;

  union frag { unsigned u[4]; short8_t v; };

  // Q fragments for the wave's 4 q-tiles (Q already pre-scaled)
  frag qf[4];
#pragma unroll
  for (int it = 0; it < 4; ++it) {
    const int n = (wv * 4 + it) * 16 + ln;
    const uint4 qd = *(const uint4*)(Qg + n * 32 + g * 8);
    qf[it].u[0] = qd.x; qf[it].u[1] = qd.y; qf[it].u[2] = qd.z; qf[it].u[3] = qd.w;
  }
  f32x4 o0[4], o1[4], sumac[4];
#pragma unroll
  for (int it = 0; it < 4; ++it) {
    o0[it] = (f32x4)(0.0f); o1[it] = (f32x4)(0.0f); sumac[it] = (f32x4)(0.0f);
  }
  frag ones;
  ones.u[0] = 0x3F803F80u; ones.u[1] = 0x3F803F80u;
  ones.u[2] = 0x3F803F80u; ones.u[3] = 0x3F803F80u;

  // bias fragment stream (fp32, D-fragment order)
  const f32x4* bp = (const f32x4*)g_biasC +
      ((size_t)(nh * 32 + wv * 4) * 16) * 128 + l * 2;

  int nA[4];
#pragma unroll
  for (int it = 0; it < 4; ++it) nA[it] = ((wv * 4 + it) * 16 + ln) & bm;

#define CLOOP(MASKED)                                                          \
  _Pragma("unroll 1")                                                          \
  for (int c = 0; c < 16; ++c) {                                               \
    frag k0, k1, a0, a1;                                                       \
    k0.v = *(const short8_t*)((const char*)Klds +                              \
        (((2 * c) * 16 + ln) * 64 + ((g * 16) ^ ((ln & 3) << 4))));            \
    k1.v = *(const short8_t*)((const char*)Klds +                              \
        (((2 * c + 1) * 16 + ln) * 64 + ((g * 16) ^ ((ln & 3) << 4))));        \
    {                                                                          \
      const int col = c * 32 + g * 4;                                          \
      const unsigned* v00 = (const unsigned*)&Vt[ln * 516 + col];              \
      const unsigned* v01 = (const unsigned*)&Vt[ln * 516 + col + 16];         \
      a0.u[0] = v00[0]; a0.u[1] = v00[1]; a0.u[2] = v01[0]; a0.u[3] = v01[1];  \
      const unsigned* v10 = (const unsigned*)&Vt[(16 + ln) * 516 + col];       \
      const unsigned* v11 = (const unsigned*)&Vt[(16 + ln) * 516 + col + 16];  \
      a1.u[0] = v10[0]; a1.u[1] = v10[1]; a1.u[2] = v11[0]; a1.u[3] = v11[1];  \
    }                                                                          \
    const int mAnd = ((c << 5) | ((g & 1) << 2)) & bm;                         \
    __builtin_amdgcn_s_setprio(1);                                             \
    _Pragma("unroll")                                                          \
    for (int it = 0; it < 4; ++it) {                                           \
      const f32x4 bc0 = bp[(it * 16 + c) * 128];                               \
      const f32x4 bc1 = bp[(it * 16 + c) * 128 + 1];                           \
      f32x4 acc0 = __builtin_amdgcn_mfma_f32_16x16x32_bf16(                    \
          k0.v, qf[it].v, bc0, 0, 0, 0);                                       \
      f32x4 acc1 = __builtin_amdgcn_mfma_f32_16x16x32_bf16(                    \
          k1.v, qf[it].v, bc1, 0, 0, 0);                                       \
      float p0 = __builtin_amdgcn_exp2f(acc0[0]);                              \
      float p1 = __builtin_amdgcn_exp2f(acc0[1]);                              \
      float p2 = __builtin_amdgcn_exp2f(acc0[2]);                              \
      float p3 = __builtin_amdgcn_exp2f(acc0[3]);                              \
      float p4 = __builtin_amdgcn_exp2f(acc1[0]);                              \
      float p5 = __builtin_amdgcn_exp2f(acc1[1]);                              \
      float p6 = __builtin_amdgcn_exp2f(acc1[2]);                              \
      float p7 = __builtin_amdgcn_exp2f(acc1[3]);                              \
      frag pf;                                                                 \
      pf.u[0] = pkbf2(p0, p1);  pf.u[1] = pkbf2(p2, p3);                       \
      pf.u[2] = pkbf2(p4, p5);  pf.u[3] = pkbf2(p6, p7);                       \
      if (MASKED) {                                                            \
        const bool keep = (nA[it] == mAnd);                                    \
        pf.u[0] = keep ? pf.u[0] : 0u;                                         \
        pf.u[1] = keep ? pf.u[1] : 0u;                                         \
        pf.u[2] = keep ? pf.u[2] : 0u;                                         \
        pf.u[3] = keep ? pf.u[3] : 0u;                                         \
      }                                                                        \
      sumac[it] = __builtin_amdgcn_mfma_f32_16x16x32_bf16(                     \
          ones.v, pf.v, sumac[it], 0, 0, 0);                                   \
      o0[it] = __builtin_amdgcn_mfma_f32_16x16x32_bf16(a0.v, pf.v, o0[it], 0, 0, 0); \
      o1[it] = __builtin_amdgcn_mfma_f32_16x16x32_bf16(a1.v, pf.v, o1[it], 0, 0, 0); \
    }                                                                          \
    __builtin_amdgcn_s_setprio(0);                                             \
  }

  if (bm == 0) { CLOOP(false) } else { CLOOP(true) }
#undef CLOOP

  // ---- epilogue: every lane's sumac[it][0] is its own full row-sum ----
#pragma unroll
  for (int it = 0; it < 4; ++it) {
    const float rinv = 1.0f / sumac[it][0];
    const int qt = wv * 4 + it;
    unsigned short* gop = g_opack + ((size_t)nh * 64 + w) * 16384 + qt * 512 + ln;
#pragma unroll
    for (int r = 0; r < 4; ++r) {
      gop[(g * 4 + r) * 16] = f2bf(o0[it][r] * rinv);
      gop[(g * 4 + r + 16) * 16] = f2bf(o1[it][r] * rinv);
    }
  }
}

// ---------------- pass 3: unpack g_opack (bf16) -> out (fp32) ----------------
__global__ __launch_bounds__(256) void unpack_kernel(float* __restrict__ out) {
  __shared__ float S[32 * 388];             // 48.5 KB
  const int bid = blockIdx.x;               // 64*16 = 1024
  const int mc = bid & 15;
  const int w = bid >> 4;
  const int dblk = w >> 4, hblk = (w >> 2) & 3, wblk = w & 3;
  const int d0 = dblk * 8 + 4, h0 = hblk * 8 + 4, w0 = wblk * 8 + 4;
  const int tid = threadIdx.x;

  // load: gop[nh][w][qt][hd][tk16] (bf16) -> regs (pinned) -> S[ml][hd*12+nh]
  uint4 db[6];
#pragma unroll
  for (int rep = 0; rep < 6; ++rep) {
    int task = rep * 256 + tid;             // 0..1535
    int tk8 = task & 1;
    int q2 = (task >> 1) & 1;
    int hd = (task >> 2) & 31;
    int nh = task >> 7;                     // 0..11
    db[rep] = *(const uint4*)(g_opack +
        ((size_t)nh * 64 + w) * 16384 + (size_t)(mc * 2 + q2) * 512 + hd * 16 + tk8 * 8);
  }
#pragma unroll
  for (int rep = 0; rep < 6; ++rep) pinu4(db[rep]);
  __builtin_amdgcn_sched_barrier(0);
#pragma unroll
  for (int rep = 0; rep < 6; ++rep) {
    int task = rep * 256 + tid;
    int tk8 = task & 1;
    int q2 = (task >> 1) & 1;
    int hd = (task >> 2) & 31;
    int nh = task >> 7;
    const unsigned u[4] = {db[rep].x, db[rep].y, db[rep].z, db[rep].w};
#pragma unroll
    for (int jj = 0; jj < 8; ++jj) {
      unsigned bits = (u[jj >> 1] << (16 * (1 - (jj & 1)))) & 0xffff0000u;
      S[(q2 * 16 + tk8 * 8 + jj) * 388 + hd * 12 + nh] = __uint_as_float(bits);
    }
  }
  __syncthreads();

  // store: token-major, fully coalesced full-line writes
#pragma unroll
  for (int rep = 0; rep < 12; ++rep) {
    int task = rep * 256 + tid;             // 0..3071
    unsigned c4 = (unsigned)task % 96u;
    int ml = (int)((unsigned)task / 96u);
    int n = mc * 32 + ml;
    int dd = (d0 + (n >> 6)) & 31;
    int hh = (h0 + ((n >> 3) & 7)) & 31;
    int ww = (w0 + (n & 7)) & 31;
    const float4* src = (const float4*)&S[ml * 388 + c4 * 4];
    *(float4*)(out + ((size_t)((dd * 32 + hh) * 32 + ww)) * 384 + c4 * 4) = *src;
  }
}

extern "C" void kernel_launch(void* const* d_in, const int* in_sizes, int n_in,
                              void* d_out, int out_size, void* d_ws, size_t ws_size,
                              hipStream_t stream) {
  (void)in_sizes; (void)n_in; (void)out_size; (void)d_ws; (void)ws_size;
  const float* qkv = (const float*)d_in[0];          // [1,32,32,32,1152] fp32
  const float* bias_table = (const float*)d_in[1];   // [3375,12] fp32
  float* out = (float*)d_out;                        // [1,32,32,32,384] fp32

  prep_kernel<<<5632, 256, 0, stream>>>(qkv, bias_table);
  swin_attn_kernel<<<768, 512, 0, stream>>>();
  unpack_kernel<<<1024, 256, 0, stream>>>(out);
}

// Round 11
// 120.218 us; speedup vs baseline: 1.0097x; 1.0082x over previous
//
#include <hip/hip_runtime.h>
#include <hip/hip_bf16.h>

// 3D shifted-window attention (Swin), D=H=W=32, WS=8, SS=4, NH=12, HD=32, N=512.
// Pass 1 (prep): [blocks 0..4095] repack qkv fp32 -> bf16:
//                  Q: g_pack[0][nh][w][m][hd]          (pre-scaled scale*log2e)
//                  K: g_pack[1][nh][w][m][hd^swz]      (XOR-swizzle pre-baked)
//                  V: g_pack[2][nh][w][mb8][hd][8]     (8-token tiles, attn-ready)
//                Phase 1 = async DMA: global_load_lds dwordx4 stages raw fp32
//                into LDS (8 vox x 5136B, +16B/voxel pad for bank spread);
//                rounds 8-10 proved synchronous reg-staging stays latency-bound
//                (~2 TB/s, VALUBusy 11%) regardless of pinning.
//                Phase 2 = LDS fp32 -> scale/cvt_pk -> packed uint4 stores.
//                [blocks 4096..5631] bias -> fp32 g_biasC (bias*log2e) in exact
//                S^T D-fragment order, fed to the QK MFMA as the C operand.
// Pass 2 (attn): one block per (window,head), 512 thr, 8 waves x 4 q-tiles.
//         K + V^T staged to LDS by pure linear copies (transposes pre-baked).
//         Per c: load K/V frags once, feed 4 q-tiles. acc = mfma(K,Q,biasC);
//         p = v_exp_f32(acc); pack (cvt_pk); row-sum via ones-MFMA; mask via
//         cndmask on packed words; o += mfma(Vt, pf). setprio(1) around core.
//         Output -> g_opack (bf16) [nh][w][qt][hd][tk16].
// Pass 3: unpack g_opack (bf16) -> out[vox][hd*12+nh] fp32 via LDS transpose.

typedef __attribute__((ext_vector_type(8))) short short8_t;   // 8 x bf16
typedef __attribute__((ext_vector_type(4))) float f32x4;

__device__ float g_biasC[12 * 32 * 16 * 64 * 8];              // 12.6 MB fp32
__device__ uint4 g_pack4[3ULL * 12 * 64 * 512 * 32 / 8];      // 75.5 MB bf16
__device__ unsigned short g_opack[12ULL * 64 * 32 * 512];     // 25.2 MB bf16

constexpr float SCL2E = 0.17677669529663687f * 1.4426950408889634f; // scale*log2e
constexpr float LOG2E = 1.4426950408889634f;

__device__ __forceinline__ unsigned short f2bf(float f) {
  __hip_bfloat16 h = __float2bfloat16(f);   // RNE
  return *reinterpret_cast<unsigned short*>(&h);
}
__device__ __forceinline__ unsigned pkbf2(float lo, float hi) {
  __hip_bfloat162 h2 = __float22bfloat162_rn(make_float2(lo, hi)); // v_cvt_pk_bf16_f32
  return *reinterpret_cast<unsigned*>(&h2);
}
__device__ __forceinline__ void pinu4(uint4& u) {
  asm volatile("" : "+v"(u.x), "+v"(u.y), "+v"(u.z), "+v"(u.w));
}
// async 16B global->LDS DMA: LDS dest = (wave-uniform) l + lane*16
__device__ __forceinline__ void gload_lds16(const float* g, float* l) {
  __builtin_amdgcn_global_load_lds(
      (const __attribute__((address_space(1))) void*)g,
      (__attribute__((address_space(3))) void*)l, 16, 0, 0);
}

// ---------------- pass 1: repack + bias prep (merged grid) ----------------
__global__ __launch_bounds__(256, 3) void prep_kernel(
    const float* __restrict__ qkv, const float* __restrict__ table) {
  // fp32 staging: 8 voxels x 1284 floats (5136 B: 5 DMA chunks + 16 B pad ->
  // voxel stride = bank+4 -> phase-2 mw-lanes spread, 4-way max conflict)
  __shared__ __align__(16) float Sf[8 * 1284];     // 41 KB
  const int bid = blockIdx.x;
  const int tid = threadIdx.x;

  if (bid >= 4096) {
    // ---- bias part: g_biasC[flat*8 + e] = bias(n, m(e)) * log2e, fp32 ----
    int flat = (bid - 4096) * 256 + tid;    // 0..393215 = (nh, qt, c, lane)
    int l  = flat & 63;
    int c  = (flat >> 6) & 15;
    int qt = (flat >> 10) & 31;
    int nh = flat >> 15;
    int ln = l & 15, g = l >> 4;
    int n = qt * 16 + ln;
    int dn = n >> 6, hn = (n >> 3) & 7, wn = n & 7;
    float e[8];
#pragma unroll
    for (int r = 0; r < 8; ++r) {
      int m = 32 * c + (r >> 2) * 16 + g * 4 + (r & 3);
      int dm = m >> 6, hm = (m >> 3) & 7, wm = m & 7;
      int idx = (dn - dm + 7) * 225 + (hn - hm + 7) * 15 + (wn - wm + 7);
      e[r] = table[idx * 12 + nh];
    }
#pragma unroll
    for (int r = 0; r < 8; ++r) asm volatile("" : "+v"(e[r]));
    __builtin_amdgcn_sched_barrier(0);
#pragma unroll
    for (int r = 0; r < 8; ++r) e[r] *= LOG2E;
    *(float4*)&g_biasC[flat * 8]     = make_float4(e[0], e[1], e[2], e[3]);
    *(float4*)&g_biasC[flat * 8 + 4] = make_float4(e[4], e[5], e[6], e[7]);
    return;
  }

  // ---- repack part ----
  const int mh = bid & 7;
  const int md = (bid >> 3) & 7;
  const int w = bid >> 6;
  const int dblk = w >> 4, hblk = (w >> 2) & 3, wblk = w & 3;
  const int dd = (dblk * 8 + 4 + md) & 31;
  const int hh = (hblk * 8 + 4 + mh) & 31;
  const int w0 = wblk * 8 + 4;
  const int lane = tid & 63;
  const int wv = tid >> 6;

  // phase 1: async DMA — wave wv stages voxels {2wv, 2wv+1}, 5 chunks each
  // (chunk = 256 floats = 64 lanes x 16B; chunk 4 holds 128 floats, half-masked)
#pragma unroll
  for (int r = 0; r < 10; ++r) {
    const int v = wv * 2 + (r >= 5 ? 1 : 0);
    const int k = (r >= 5) ? (r - 5) : r;
    const int ww = (w0 + v) & 31;
    const float* g = qkv + ((dd * 32 + hh) * 32 + ww) * 1152 + k * 256 + lane * 4;
    float* l = &Sf[v * 1284 + k * 256];
    if (k < 4)            gload_lds16(g, l);
    else if (lane < 32)   gload_lds16(g, l);
  }
  __syncthreads();   // compiler emits vmcnt(0) before the barrier

  // phase 2: LDS fp32 -> scale/cvt -> packed stores (dst layout unchanged)
  const int mbase = md * 64 + mh * 8;
  unsigned short* gp = (unsigned short*)g_pack4;
#pragma unroll
  for (int rep = 0; rep < 5; ++rep) {
    int t = rep * 256 + tid;                 // 1152 tasks
    if (t < 1152) {
      int r = t >> 5;                        // 0..35
      int nh = r % 12;
      int part = r / 12;
      unsigned pk[4];
      size_t dst;
      if (part < 2) {
        // Q/K: pack 8 consecutive hd of one token
        int chunk = t & 3;
        int mw = (t >> 2) & 7;
        int fbase = mw * 1284 + part * 384 + chunk * 96 + nh;
        const float sc = (part == 0) ? SCL2E : 1.0f;
#pragma unroll
        for (int jj = 0; jj < 4; ++jj) {
          float x0 = Sf[fbase + (2 * jj) * 12] * sc;
          float x1 = Sf[fbase + (2 * jj + 1) * 12] * sc;
          pk[jj] = pkbf2(x0, x1);
        }
        int m = mbase + mw;
        int off = (part == 0) ? (m * 32 + chunk * 8)
                              : (m * 32 + ((chunk * 8) ^ ((mw & 3) << 3))); // K swz
        dst = ((size_t)(part * 12 + nh) * 64 + w) * 16384 + off;
      } else {
        // V: pack 8 consecutive tokens of one hd -> [mb8][hd][8] tile
        int hd = t & 31;
        int c = 768 + hd * 12 + nh;
#pragma unroll
        for (int jj = 0; jj < 4; ++jj) {
          float x0 = Sf[(2 * jj) * 1284 + c];
          float x1 = Sf[(2 * jj + 1) * 1284 + c];
          pk[jj] = pkbf2(x0, x1);
        }
        dst = ((size_t)(24 + nh) * 64 + w) * 16384 + (md * 8 + mh) * 256 + hd * 8;
      }
      *(uint4*)&gp[dst] = make_uint4(pk[0], pk[1], pk[2], pk[3]);
    }
  }
}

// -------- pass 2: attention (512 threads, 8 waves x 4 q-tiles, fused) --------
__global__ __launch_bounds__(512, 4) void swin_attn_kernel() {
  __shared__ __align__(16) unsigned short Klds[512 * 32];   // 32 KB, XOR-swz
  __shared__ __align__(16) unsigned short Vt[32 * 516];     // 33 KB

  const int bid = blockIdx.x;
  // Head-clustered XCD map: XCD x owns head x (64 windows) + half of head 8+x/2
  const int xcd = bid & 7;
  const int jb = bid >> 3;                   // 0..95
  int nh, w;
  if (jb < 64) { nh = xcd; w = jb; }
  else         { nh = 8 + (xcd >> 1); w = (xcd & 1) * 32 + (jb - 64); }
  const int dblk = w >> 4, hblk = (w >> 2) & 3, wblk = w & 3;
  const int bm = ((dblk == 3) ? 256 : 0) | ((hblk == 3) ? 32 : 0) |
                 ((wblk == 3) ? 4 : 0);

  const int tid = threadIdx.x;

  const unsigned short* gp = (const unsigned short*)g_pack4;
  const size_t base = ((size_t)nh * 64 + w) * (512 * 32);
  const unsigned short* Qg = gp + base;                           // part 0
  const unsigned short* Kg = gp + (size_t)1 * 12 * 64 * 512 * 32 + base;
  const unsigned short* Vg = gp + (size_t)2 * 12 * 64 * 512 * 32 + base;

  // ---- stage K + V: 8 outstanding linear uint4 loads (pinned), LDS writes ----
  uint4 kb[4], vb[4];
#pragma unroll
  for (int itr = 0; itr < 4; ++itr) kb[itr] = *(const uint4*)(Kg + (itr * 512 + tid) * 8);
#pragma unroll
  for (int itr = 0; itr < 4; ++itr) vb[itr] = *(const uint4*)(Vg + (itr * 512 + tid) * 8);
#pragma unroll
  for (int itr = 0; itr < 4; ++itr) { pinu4(kb[itr]); pinu4(vb[itr]); }
  __builtin_amdgcn_sched_barrier(0);
#pragma unroll
  for (int itr = 0; itr < 4; ++itr)
    *(uint4*)((char*)Klds + (itr * 512 + tid) * 16) = kb[itr];   // swz pre-baked
#pragma unroll
  for (int itr = 0; itr < 4; ++itr) {
    int flat = itr * 512 + tid;
    int hd = flat & 31, mb8 = flat >> 5;
    *(uint2*)&Vt[hd * 516 + mb8 * 8]     = make_uint2(vb[itr].x, vb[itr].y);
    *(uint2*)&Vt[hd * 516 + mb8 * 8 + 4] = make_uint2(vb[itr].z, vb[itr].w);
  }
  __syncthreads();

  const int l = tid & 63;
  const int wv = tid >> 6;                   // 0..7, owns q-tiles wv*4..wv*4+3
  const int ln = l & 15;
  const int g = l >> 4;

  union frag { unsigned u[4]; short8_t v; };

  // Q fragments for the wave's 4 q-tiles (Q already pre-scaled)
  frag qf[4];
#pragma unroll
  for (int it = 0; it < 4; ++it) {
    const int n = (wv * 4 + it) * 16 + ln;
    const uint4 qd = *(const uint4*)(Qg + n * 32 + g * 8);
    qf[it].u[0] = qd.x; qf[it].u[1] = qd.y; qf[it].u[2] = qd.z; qf[it].u[3] = qd.w;
  }
  f32x4 o0[4], o1[4], sumac[4];
#pragma unroll
  for (int it = 0; it < 4; ++it) {
    o0[it] = (f32x4)(0.0f); o1[it] = (f32x4)(0.0f); sumac[it] = (f32x4)(0.0f);
  }
  frag ones;
  ones.u[0] = 0x3F803F80u; ones.u[1] = 0x3F803F80u;
  ones.u[2] = 0x3F803F80u; ones.u[3] = 0x3F803F80u;

  // bias fragment stream (fp32, D-fragment order)
  const f32x4* bp = (const f32x4*)g_biasC +
      ((size_t)(nh * 32 + wv * 4) * 16) * 128 + l * 2;

  int nA[4];
#pragma unroll
  for (int it = 0; it < 4; ++it) nA[it] = ((wv * 4 + it) * 16 + ln) & bm;

#define CLOOP(MASKED)                                                          \
  _Pragma("unroll 1")                                                          \
  for (int c = 0; c < 16; ++c) {                                               \
    frag k0, k1, a0, a1;                                                       \
    k0.v = *(const short8_t*)((const char*)Klds +                              \
        (((2 * c) * 16 + ln) * 64 + ((g * 16) ^ ((ln & 3) << 4))));            \
    k1.v = *(const short8_t*)((const char*)Klds +                              \
        (((2 * c + 1) * 16 + ln) * 64 + ((g * 16) ^ ((ln & 3) << 4))));        \
    {                                                                          \
      const int col = c * 32 + g * 4;                                          \
      const unsigned* v00 = (const unsigned*)&Vt[ln * 516 + col];              \
      const unsigned* v01 = (const unsigned*)&Vt[ln * 516 + col + 16];         \
      a0.u[0] = v00[0]; a0.u[1] = v00[1]; a0.u[2] = v01[0]; a0.u[3] = v01[1];  \
      const unsigned* v10 = (const unsigned*)&Vt[(16 + ln) * 516 + col];       \
      const unsigned* v11 = (const unsigned*)&Vt[(16 + ln) * 516 + col + 16];  \
      a1.u[0] = v10[0]; a1.u[1] = v10[1]; a1.u[2] = v11[0]; a1.u[3] = v11[1];  \
    }                                                                          \
    const int mAnd = ((c << 5) | ((g & 1) << 2)) & bm;                         \
    __builtin_amdgcn_s_setprio(1);                                             \
    _Pragma("unroll")                                                          \
    for (int it = 0; it < 4; ++it) {                                           \
      const f32x4 bc0 = bp[(it * 16 + c) * 128];                               \
      const f32x4 bc1 = bp[(it * 16 + c) * 128 + 1];                           \
      f32x4 acc0 = __builtin_amdgcn_mfma_f32_16x16x32_bf16(                    \
          k0.v, qf[it].v, bc0, 0, 0, 0);                                       \
      f32x4 acc1 = __builtin_amdgcn_mfma_f32_16x16x32_bf16(                    \
          k1.v, qf[it].v, bc1, 0, 0, 0);                                       \
      float p0 = __builtin_amdgcn_exp2f(acc0[0]);                              \
      float p1 = __builtin_amdgcn_exp2f(acc0[1]);                              \
      float p2 = __builtin_amdgcn_exp2f(acc0[2]);                              \
      float p3 = __builtin_amdgcn_exp2f(acc0[3]);                              \
      float p4 = __builtin_amdgcn_exp2f(acc1[0]);                              \
      float p5 = __builtin_amdgcn_exp2f(acc1[1]);                              \
      float p6 = __builtin_amdgcn_exp2f(acc1[2]);                              \
      float p7 = __builtin_amdgcn_exp2f(acc1[3]);                              \
      frag pf;                                                                 \
      pf.u[0] = pkbf2(p0, p1);  pf.u[1] = pkbf2(p2, p3);                       \
      pf.u[2] = pkbf2(p4, p5);  pf.u[3] = pkbf2(p6, p7);                       \
      if (MASKED) {                                                            \
        const bool keep = (nA[it] == mAnd);                                    \
        pf.u[0] = keep ? pf.u[0] : 0u;                                         \
        pf.u[1] = keep ? pf.u[1] : 0u;                                         \
        pf.u[2] = keep ? pf.u[2] : 0u;                                         \
        pf.u[3] = keep ? pf.u[3] : 0u;                                         \
      }                                                                        \
      sumac[it] = __builtin_amdgcn_mfma_f32_16x16x32_bf16(                     \
          ones.v, pf.v, sumac[it], 0, 0, 0);                                   \
      o0[it] = __builtin_amdgcn_mfma_f32_16x16x32_bf16(a0.v, pf.v, o0[it], 0, 0, 0); \
      o1[it] = __builtin_amdgcn_mfma_f32_16x16x32_bf16(a1.v, pf.v, o1[it], 0, 0, 0); \
    }                                                                          \
    __builtin_amdgcn_s_setprio(0);                                             \
  }

  if (bm == 0) { CLOOP(false) } else { CLOOP(true) }
#undef CLOOP

  // ---- epilogue: every lane's sumac[it][0] is its own full row-sum ----
#pragma unroll
  for (int it = 0; it < 4; ++it) {
    const float rinv = 1.0f / sumac[it][0];
    const int qt = wv * 4 + it;
    unsigned short* gop = g_opack + ((size_t)nh * 64 + w) * 16384 + qt * 512 + ln;
#pragma unroll
    for (int r = 0; r < 4; ++r) {
      gop[(g * 4 + r) * 16] = f2bf(o0[it][r] * rinv);
      gop[(g * 4 + r + 16) * 16] = f2bf(o1[it][r] * rinv);
    }
  }
}

// ---------------- pass 3: unpack g_opack (bf16) -> out (fp32) ----------------
__global__ __launch_bounds__(256) void unpack_kernel(float* __restrict__ out) {
  __shared__ float S[32 * 388];             // 48.5 KB
  const int bid = blockIdx.x;               // 64*16 = 1024
  const int mc = bid & 15;
  const int w = bid >> 4;
  const int dblk = w >> 4, hblk = (w >> 2) & 3, wblk = w & 3;
  const int d0 = dblk * 8 + 4, h0 = hblk * 8 + 4, w0 = wblk * 8 + 4;
  const int tid = threadIdx.x;

  // load: gop[nh][w][qt][hd][tk16] (bf16) -> regs (pinned) -> S[ml][hd*12+nh]
  uint4 db[6];
#pragma unroll
  for (int rep = 0; rep < 6; ++rep) {
    int task = rep * 256 + tid;             // 0..1535
    int tk8 = task & 1;
    int q2 = (task >> 1) & 1;
    int hd = (task >> 2) & 31;
    int nh = task >> 7;                     // 0..11
    db[rep] = *(const uint4*)(g_opack +
        ((size_t)nh * 64 + w) * 16384 + (size_t)(mc * 2 + q2) * 512 + hd * 16 + tk8 * 8);
  }
#pragma unroll
  for (int rep = 0; rep < 6; ++rep) pinu4(db[rep]);
  __builtin_amdgcn_sched_barrier(0);
#pragma unroll
  for (int rep = 0; rep < 6; ++rep) {
    int task = rep * 256 + tid;
    int tk8 = task & 1;
    int q2 = (task >> 1) & 1;
    int hd = (task >> 2) & 31;
    int nh = task >> 7;
    const unsigned u[4] = {db[rep].x, db[rep].y, db[rep].z, db[rep].w};
#pragma unroll
    for (int jj = 0; jj < 8; ++jj) {
      unsigned bits = (u[jj >> 1] << (16 * (1 - (jj & 1)))) & 0xffff0000u;
      S[(q2 * 16 + tk8 * 8 + jj) * 388 + hd * 12 + nh] = __uint_as_float(bits);
    }
  }
  __syncthreads();

  // store: token-major, fully coalesced full-line writes
#pragma unroll
  for (int rep = 0; rep < 12; ++rep) {
    int task = rep * 256 + tid;             // 0..3071
    unsigned c4 = (unsigned)task % 96u;
    int ml = (int)((unsigned)task / 96u);
    int n = mc * 32 + ml;
    int dd = (d0 + (n >> 6)) & 31;
    int hh = (h0 + ((n >> 3) & 7)) & 31;
    int ww = (w0 + (n & 7)) & 31;
    const float4* src = (const float4*)&S[ml * 388 + c4 * 4];
    *(float4*)(out + ((size_t)((dd * 32 + hh) * 32 + ww)) * 384 + c4 * 4) = *src;
  }
}

extern "C" void kernel_launch(void* const* d_in, const int* in_sizes, int n_in,
                              void* d_out, int out_size, void* d_ws, size_t ws_size,
                              hipStream_t stream) {
  (void)in_sizes; (void)n_in; (void)out_size; (void)d_ws; (void)ws_size;
  const float* qkv = (const float*)d_in[0];          // [1,32,32,32,1152] fp32
  const float* bias_table = (const float*)d_in[1];   // [3375,12] fp32
  float* out = (float*)d_out;                        // [1,32,32,32,384] fp32

  prep_kernel<<<5632, 256, 0, stream>>>(qkv, bias_table);
  swin_attn_kernel<<<768, 512, 0, stream>>>();
  unpack_kernel<<<1024, 256, 0, stream>>>(out);
}